// Round 7
// baseline (149.815 us; speedup 1.0000x reference)
//
#include <hip/hip_runtime.h>
#include <math.h>

#define BATCH   4096
#define N_NODES 20000
#define H       4
#define BLOCK   512
#define NW      (BLOCK / 64)
#define ROWS    4
#define GRID    (BATCH / ROWS)

constexpr int LSTART_C[H] = {0, 100, 1100, 6100};
constexpr int LSIZE_C[H]  = {100, 1000, 5000, 13900};

__device__ __forceinline__ float waveSum(float v) {
#pragma unroll
    for (int off = 32; off > 0; off >>= 1) v += __shfl_xor(v, off);
    return v;
}
__device__ __forceinline__ float bf2f(ushort h) {
    return __uint_as_float(((unsigned)h) << 16);
}
__device__ __forceinline__ ushort f2bf_trunc(float x) {
    return (ushort)(__float_as_uint(x) >> 16);
}

// phase 1 only (row 0): stream y_pred(+y_true), stage bf16(e) to LDS, accumulate sums
template<int L>
__device__ __forceinline__ void p1_layer(const float4* yp4, const float4* yt4,
    ushort* row_bf, float& z, float& q2, float& dt, float& ys, int tid)
{
    constexpr int SQ = LSTART_C[L] / 4, NQ = LSIZE_C[L] / 4;
    for (int i = tid; i < NQ; i += BLOCK) {
        float4 v = yp4[SQ + i];
        float e0 = __expf(v.x), e1 = __expf(v.y), e2 = __expf(v.z), e3 = __expf(v.w);
        ushort4 h;
        h.x = f2bf_trunc(e0); h.y = f2bf_trunc(e1);
        h.z = f2bf_trunc(e2); h.w = f2bf_trunc(e3);
        *reinterpret_cast<ushort4*>(&row_bf[4 * (SQ + i)]) = h;
        z += (e0 + e1) + (e2 + e3);
        if constexpr (L > 0) {
            q2 += (e0*e0 + e1*e1) + (e2*e2 + e3*e3);
            float4 t = yt4[SQ + i];
            dt += t.x*e0 + t.y*e1 + t.z*e2 + t.w*e3;
            ys += (t.x + t.y) + (t.z + t.w);
        }
    }
}

// phase 2 only (last row): D_l = sum relu(e*invZ - e_pa*invZp), read-only on LDS
template<int L>
__device__ __forceinline__ void p2_layer(const int4* pa4, const ushort* row_bf,
    const float* invZ_s, float& D, int tid)
{
    constexpr int S = LSTART_C[L], SQ = S / 4, NQ = LSIZE_C[L] / 4;
    const float invZ = invZ_s[L], invZp = invZ_s[L - 1];
    for (int i = tid; i < NQ; i += BLOCK) {
        ushort4 h = *reinterpret_cast<const ushort4*>(&row_bf[S + 4 * i]);
        int4 pa = pa4[SQ + i];
        float p0 = bf2f(h.x)*invZ, p1 = bf2f(h.y)*invZ;
        float p2 = bf2f(h.z)*invZ, p3 = bf2f(h.w)*invZ;
        float pp0 = bf2f(row_bf[pa.x])*invZp, pp1 = bf2f(row_bf[pa.y])*invZp;
        float pp2 = bf2f(row_bf[pa.z])*invZp, pp3 = bf2f(row_bf[pa.w])*invZp;
        D += (fmaxf(p0-pp0,0.f)+fmaxf(p1-pp1,0.f)) + (fmaxf(p2-pp2,0.f)+fmaxf(p3-pp3,0.f));
    }
}

// fused: phase 2 of row k (LDS) rides under phase 1 stream of row k+1 (global).
// phase2 reads child quad i (layer L) then phase1 overwrites the SAME quad (same
// thread -> no race); parent reads hit layer L-1, untouched until next segment.
template<int L>
__device__ __forceinline__ void fused_layer(const float4* yp4n, const float4* yt4n,
    const int4* pa4, ushort* row_bf, const float* invZ_s,
    float& z, float& q2, float& dt, float& ys, float& D, int tid)
{
    constexpr int S = LSTART_C[L], SQ = S / 4, NQ = LSIZE_C[L] / 4;
    const float invZ = invZ_s[L], invZp = invZ_s[L - 1];
    for (int i = tid; i < NQ; i += BLOCK) {
        float4 v = yp4n[SQ + i];     // next-row loads issued first
        float4 t = yt4n[SQ + i];
        int4  pa = pa4[SQ + i];      // parent idx: row-invariant, L2-resident
        // ---- phase 2 on current row (LDS + VALU hides the load latency) ----
        ushort4 h = *reinterpret_cast<const ushort4*>(&row_bf[S + 4 * i]);
        float p0 = bf2f(h.x)*invZ, p1 = bf2f(h.y)*invZ;
        float p2 = bf2f(h.z)*invZ, p3 = bf2f(h.w)*invZ;
        float pp0 = bf2f(row_bf[pa.x])*invZp, pp1 = bf2f(row_bf[pa.y])*invZp;
        float pp2 = bf2f(row_bf[pa.z])*invZp, pp3 = bf2f(row_bf[pa.w])*invZp;
        D += (fmaxf(p0-pp0,0.f)+fmaxf(p1-pp1,0.f)) + (fmaxf(p2-pp2,0.f)+fmaxf(p3-pp3,0.f));
        // ---- phase 1 for next row ----
        float e0 = __expf(v.x), e1 = __expf(v.y), e2 = __expf(v.z), e3 = __expf(v.w);
        ushort4 hn;
        hn.x = f2bf_trunc(e0); hn.y = f2bf_trunc(e1);
        hn.z = f2bf_trunc(e2); hn.w = f2bf_trunc(e3);
        *reinterpret_cast<ushort4*>(&row_bf[S + 4 * i]) = hn;
        z  += (e0 + e1) + (e2 + e3);
        q2 += (e0*e0 + e1*e1) + (e2*e2 + e3*e3);
        dt += t.x*e0 + t.y*e1 + t.z*e2 + t.w*e3;
        ys += (t.x + t.y) + (t.z + t.w);
    }
}

__global__ __launch_bounds__(BLOCK, 8) void tax_main(
    const float* __restrict__ y_pred,
    const float* __restrict__ y_true,
    const int*   __restrict__ parents,
    const float* __restrict__ alpha,
    float*       __restrict__ partial)
{
    __shared__ __align__(8) ushort row_bf[N_NODES];   // 40,000 B: bf16(e) of current row
    __shared__ float sc[NW * 20];                     // 640 B reduce staging
    __shared__ float invZ_s[H];
    __shared__ float contribL[H];
    __shared__ float carry;                           // cce part of previous row

    const int tid = threadIdx.x;
    const int wid = tid >> 6;
    const int lid = tid & 63;
    const int r0  = blockIdx.x * ROWS;
    const int4* pa4 = reinterpret_cast<const int4*>(parents);

    float z[H], q2[H], dt[H], ys[H], D[H];   // static indexing only

    auto reduce_step = [&](bool writePrev, int prevRow) {
        float rz0 = waveSum(z[0]);
        float r1[3], r2[3], r3[3], r4[3], rD[3];
#pragma unroll
        for (int l = 1; l < H; ++l) {
            r1[l-1] = waveSum(z[l]);  r2[l-1] = waveSum(q2[l]);
            r3[l-1] = waveSum(dt[l]); r4[l-1] = waveSum(ys[l]);
            rD[l-1] = writePrev ? waveSum(D[l]) : 0.f;
        }
        if (lid == 0) {
            float* p = &sc[wid * 20];
            p[0] = rz0;
#pragma unroll
            for (int j = 0; j < 3; ++j) {
                p[1+j] = r1[j]; p[4+j] = r2[j]; p[7+j] = r3[j];
                p[10+j] = r4[j]; p[13+j] = rD[j];
            }
        }
        __syncthreads();
        if (tid < H) {
            const int l = tid;
            float zt = 0.f, q2t = 0.f, dtt = 0.f, yst = 0.f;
            for (int w = 0; w < NW; ++w) {
                const float* p = &sc[w * 20];
                if (l == 0) zt += p[0];
                else { zt += p[1+(l-1)]; q2t += p[4+(l-1)]; dtt += p[7+(l-1)]; yst += p[10+(l-1)]; }
            }
            float invZ = 1.f / zt;
            invZ_s[l] = invZ;
            if (l > 0) {
                float S = (float)(LSIZE_C[l] + 1) + 0.5f * q2t * invZ * invZ;  // sum exp(p) ~ n+1+0.5*sum p^2
                contribL[l] = alpha[l] * (logf(S) * yst - dtt * invZ);
            }
        }
        if (tid == 0 && writePrev) {
            float acc = carry;
#pragma unroll
            for (int j = 0; j < 3; ++j) {
                float Dl = 0.f;
                for (int w = 0; w < NW; ++w) Dl += sc[w * 20 + 13 + j];
                acc += alpha[j+1] * Dl / (float)LSIZE_C[j+1];
            }
            partial[prevRow] = acc;
        }
        __syncthreads();
        if (tid == 0) carry = contribL[1] + contribL[2] + contribL[3];  // tid0-write, tid0-read
    };

    // ---- head: row 0 phase 1 (pure stream) ----
    {
        const float4* yp4 = reinterpret_cast<const float4*>(y_pred + (size_t)r0 * N_NODES);
        const float4* yt4 = reinterpret_cast<const float4*>(y_true + (size_t)r0 * N_NODES);
#pragma unroll
        for (int l = 0; l < H; ++l) { z[l]=0.f; q2[l]=0.f; dt[l]=0.f; ys[l]=0.f; D[l]=0.f; }
        p1_layer<3>(yp4, yt4, row_bf, z[3], q2[3], dt[3], ys[3], tid);
        p1_layer<2>(yp4, yt4, row_bf, z[2], q2[2], dt[2], ys[2], tid);
        p1_layer<1>(yp4, yt4, row_bf, z[1], q2[1], dt[1], ys[1], tid);
        p1_layer<0>(yp4, yt4, row_bf, z[0], q2[0], dt[0], ys[0], tid);
    }
    reduce_step(false, 0);

    // ---- pipelined middle: phase2(row k) fused under phase1(row k+1), layers 3->0 ----
#pragma unroll 1
    for (int k = 0; k < ROWS - 1; ++k) {
        const float4* yp4n = reinterpret_cast<const float4*>(y_pred + (size_t)(r0 + k + 1) * N_NODES);
        const float4* yt4n = reinterpret_cast<const float4*>(y_true + (size_t)(r0 + k + 1) * N_NODES);
#pragma unroll
        for (int l = 0; l < H; ++l) { z[l]=0.f; q2[l]=0.f; dt[l]=0.f; ys[l]=0.f; D[l]=0.f; }
        fused_layer<3>(yp4n, yt4n, pa4, row_bf, invZ_s, z[3], q2[3], dt[3], ys[3], D[3], tid);
        __syncthreads();   // l3 parent reads (l2) done before fused<2> overwrites l2
        fused_layer<2>(yp4n, yt4n, pa4, row_bf, invZ_s, z[2], q2[2], dt[2], ys[2], D[2], tid);
        __syncthreads();   // l2 parent reads (l1) done before fused<1> overwrites l1
        fused_layer<1>(yp4n, yt4n, pa4, row_bf, invZ_s, z[1], q2[1], dt[1], ys[1], D[1], tid);
        __syncthreads();   // l1 parent reads (l0) done before p1<0> overwrites l0
        p1_layer<0>(yp4n, yt4n, row_bf, z[0], q2[0], dt[0], ys[0], tid);
        reduce_step(true, r0 + k);
    }

    // ---- tail: phase 2 of last row (read-only on LDS, no barriers needed) ----
#pragma unroll
    for (int l = 0; l < H; ++l) D[l] = 0.f;
    p2_layer<3>(pa4, row_bf, invZ_s, D[3], tid);
    p2_layer<2>(pa4, row_bf, invZ_s, D[2], tid);
    p2_layer<1>(pa4, row_bf, invZ_s, D[1], tid);
    {
        float rD1 = waveSum(D[1]), rD2 = waveSum(D[2]), rD3 = waveSum(D[3]);
        if (lid == 0) {
            sc[wid * 20 + 13] = rD1; sc[wid * 20 + 14] = rD2; sc[wid * 20 + 15] = rD3;
        }
        __syncthreads();
        if (tid == 0) {
            float acc = carry;
#pragma unroll
            for (int j = 0; j < 3; ++j) {
                float Dl = 0.f;
                for (int w = 0; w < NW; ++w) Dl += sc[w * 20 + 13 + j];
                acc += alpha[j+1] * Dl / (float)LSIZE_C[j+1];
            }
            partial[r0 + ROWS - 1] = acc;
        }
    }
}

__global__ __launch_bounds__(1024) void tax_reduce(
    const float* __restrict__ partial, float* __restrict__ out)
{
    __shared__ float red[16];
    const int tid = threadIdx.x, wid = tid >> 6, lid = tid & 63;
    float v = 0.f;
    for (int i = tid; i < BATCH; i += 1024) v += partial[i];
    v = waveSum(v);
    if (lid == 0) red[wid] = v;
    __syncthreads();
    if (wid == 0) {
        float x = (lid < 16) ? red[lid] : 0.f;
        x = waveSum(x);
        if (lid == 0) out[0] = x * (1.0f / (float)BATCH);
    }
}

extern "C" void kernel_launch(void* const* d_in, const int* in_sizes, int n_in,
                              void* d_out, int out_size, void* d_ws, size_t ws_size,
                              hipStream_t stream) {
    const float* y_pred  = (const float*)d_in[0];
    const float* y_true  = (const float*)d_in[1];
    const int*   parents = (const int*)d_in[2];
    const float* alpha   = (const float*)d_in[3];
    float* partial = (float*)d_ws;           // BATCH floats = 16 KB scratch
    float* out     = (float*)d_out;

    tax_main<<<dim3(GRID), dim3(BLOCK), 0, stream>>>(y_pred, y_true, parents, alpha, partial);
    tax_reduce<<<dim3(1), dim3(1024), 0, stream>>>(partial, out);
}